// Round 9
// baseline (780.862 us; speedup 1.0000x reference)
//
#include <hip/hip_runtime.h>

// ---------------------------------------------------------------------------
// RingDilatedAttentionSDPA: B=1, S=8192, E=1024, H=16, D=64
// segments: (len=2048,dil=1), (4096,2), (8192->2048,4); mean of scattered outs
// Pipeline: cvt_all f32->bf16 ; QKV GEMM (C^T epilogue) -> Q(log2e/8),K,V
// [h][s][d] ; transpose_v -> 3 key-permuted V^T copies ; flash: 2048 blocks
// of 64 q-rows, BARRIER-FREE K-loop (each wave owns Nk/4 keys + private 8KB
// LDS, register-prefetched; S^T=K.Q^T, O^T=V^T.P^T with in-register P^T),
// end-of-block LDS-atomic merge -> fully normalized per-seg output ;
// combine (plain 3-way sum) ; out GEMM (C^T).
// ---------------------------------------------------------------------------

typedef __attribute__((ext_vector_type(8))) short bf16x8;   // 8 bf16 in 4 VGPRs
typedef __attribute__((ext_vector_type(4))) float f32x4;

#define MFMA(a, b, c) __builtin_amdgcn_mfma_f32_16x16x32_bf16((a), (b), (c), 0, 0, 0)

#if __has_builtin(__builtin_amdgcn_exp2f)
#define EXP2(x) __builtin_amdgcn_exp2f(x)
#else
#define EXP2(x) exp2f(x)
#endif

static __device__ __forceinline__ unsigned short f2bf(float f) {
  unsigned int u = __float_as_uint(f);
  unsigned int r = (u + 0x7FFFu + ((u >> 16) & 1u)) >> 16;  // RNE
  return (unsigned short)r;
}

// ---------------------------- f32 -> bf16 convert (fused 3 tensors) --------
__global__ void cvt_all(const float* __restrict__ x, const float* __restrict__ wq,
                        const float* __restrict__ wo,
                        unsigned short* __restrict__ xb,
                        unsigned short* __restrict__ wqb,
                        unsigned short* __restrict__ wob) {
  int i = blockIdx.x * 256 + threadIdx.x;     // 1572864 slots of 8 elems
  const float* src;
  unsigned short* dst;
  if (i < 1048576) { src = x; dst = xb; }
  else if (i < 1441792) { i -= 1048576; src = wq; dst = wqb; }
  else { i -= 1441792; src = wo; dst = wob; }
  const float4* p = (const float4*)src + (size_t)i * 2;
  float4 a = p[0];
  float4 b = p[1];
  union { bf16x8 v; unsigned short u[8]; } o;
  o.u[0] = f2bf(a.x); o.u[1] = f2bf(a.y); o.u[2] = f2bf(a.z); o.u[3] = f2bf(a.w);
  o.u[4] = f2bf(b.x); o.u[5] = f2bf(b.y); o.u[6] = f2bf(b.z); o.u[7] = f2bf(b.w);
  *((bf16x8*)dst + i) = o.v;
}

// ------------------------------- GEMM (C = A.B^T + bias) -------------------
// Computes C^T tiles (rows=features, cols=s) -> vectorized epilogue stores.
// EPILOGUE 0: qkv [3][16][8192][64] bf16 (Q scaled log2e/8), 8B stores;
// EPILOGUE 1: f32 row-major, 16B stores.
template <int EPILOGUE>
__global__ __launch_bounds__(256, 2) void gemm_bt(
    const unsigned short* __restrict__ A, const unsigned short* __restrict__ B,
    const float* __restrict__ bias, void* __restrict__ Cout, int N, int K) {
  __shared__ unsigned short At[128 * 32];
  __shared__ unsigned short Bt[128 * 32];
  const int tid = threadIdx.x;
  const int wave = tid >> 6, lane = tid & 63;
  const int quad = lane >> 4, lc = lane & 15;
  const int wm = (wave >> 1) * 64, wn = (wave & 1) * 64;
  const int m0 = blockIdx.x * 128, n0 = blockIdx.y * 128;

  f32x4 acc[4][4] = {};

  for (int k0 = 0; k0 < K; k0 += 32) {
    __syncthreads();
#pragma unroll
    for (int issue = 0; issue < 2; ++issue) {
      const int cbase = issue * 256 + wave * 64;
      const int c = cbase + lane;
      const int row = c >> 2, col8 = (c & 3) * 8;   // 128 rows x 32 cols
      __builtin_amdgcn_global_load_lds(
          (const __attribute__((address_space(1))) void*)&A[(size_t)(m0 + row) * K + k0 + col8],
          (__attribute__((address_space(3))) void*)&At[cbase * 8], 16, 0, 0);
      __builtin_amdgcn_global_load_lds(
          (const __attribute__((address_space(1))) void*)&B[(size_t)(n0 + row) * K + k0 + col8],
          (__attribute__((address_space(3))) void*)&Bt[cbase * 8], 16, 0, 0);
    }
    __syncthreads();
    bf16x8 af[4], bfr[4];
#pragma unroll
    for (int t = 0; t < 4; ++t)
      af[t] = *(const bf16x8*)&At[(wm + t * 16 + lc) * 32 + quad * 8];
#pragma unroll
    for (int t = 0; t < 4; ++t)
      bfr[t] = *(const bf16x8*)&Bt[(wn + t * 16 + lc) * 32 + quad * 8];
#pragma unroll
    for (int i = 0; i < 4; ++i)
#pragma unroll
      for (int j = 0; j < 4; ++j)
        acc[i][j] = MFMA(bfr[j], af[i], acc[i][j]);   // C^T: rows=feat, cols=s
  }

#pragma unroll
  for (int j = 0; j < 4; ++j) {
    const int nc0 = n0 + wn + j * 16 + quad * 4;      // 4 consecutive features
    const float4 bs4 = *(const float4*)&bias[nc0];
    if (EPILOGUE == 0) {
      const int which = nc0 >> 10, rem = nc0 & 1023;
      const int hh = rem >> 6, d0 = rem & 63;
      const float sc = (which == 0) ? 0.18033688f : 1.0f;  // log2e/8 for Q
      unsigned short* base =
          (unsigned short*)Cout + ((size_t)(which * 16 + hh)) * 8192 * 64 + d0;
#pragma unroll
      for (int i = 0; i < 4; ++i) {
        const int grow = m0 + wm + i * 16 + lc;
        const unsigned int p0 = __float_as_uint((acc[i][j][0] + bs4.x) * sc) + 0x8000u;
        const unsigned int p1 = __float_as_uint((acc[i][j][1] + bs4.y) * sc) + 0x8000u;
        const unsigned int p2 = __float_as_uint((acc[i][j][2] + bs4.z) * sc) + 0x8000u;
        const unsigned int p3 = __float_as_uint((acc[i][j][3] + bs4.w) * sc) + 0x8000u;
        uint2 w;
        w.x = __builtin_amdgcn_perm(p1, p0, 0x07060302u);
        w.y = __builtin_amdgcn_perm(p3, p2, 0x07060302u);
        *(uint2*)(base + (size_t)grow * 64) = w;
      }
    } else {
      float* op = (float*)Cout;
#pragma unroll
      for (int i = 0; i < 4; ++i) {
        const int grow = m0 + wm + i * 16 + lc;
        float4 v;
        v.x = acc[i][j][0] + bs4.x;
        v.y = acc[i][j][1] + bs4.y;
        v.z = acc[i][j][2] + bs4.z;
        v.w = acc[i][j][3] + bs4.w;
        *(float4*)&op[(size_t)grow * N + nc0] = v;
      }
    }
  }
}

// ---------------- V transpose: [h][s][d] -> key-permuted [h][d][n] ---------
// perm within each 32-block: position p holds key 16*((p>>2)&1)+4*(p>>3)+(p&3)
__global__ void transpose_v(const unsigned short* __restrict__ v,
                            unsigned short* __restrict__ vt1,
                            unsigned short* __restrict__ vt2,
                            unsigned short* __restrict__ vt3) {
  __shared__ unsigned short Tt[64 * 72];
  const int tid = threadIdx.x;
  const int h = blockIdx.y;
  const int bx = blockIdx.x;
  const unsigned short* src = v + (size_t)h * 8192 * 64;
  unsigned short* dst;
  int dil, Nk, t0;
  if (bx < 32)      { dst = vt1; dil = 1; Nk = 2048; t0 = bx; }
  else if (bx < 96) { dst = vt2; dil = 2; Nk = 4096; t0 = bx - 32; }
  else              { dst = vt3; dil = 4; Nk = 2048; t0 = bx - 96; }
  dst += (size_t)h * 64 * Nk;
  const int j0 = t0 * 64;
#pragma unroll
  for (int it = 0; it < 2; ++it) {
    const int slot = tid + it * 256;
    const int jj = slot >> 3, c8 = (slot & 7) * 8;
    *(bf16x8*)&Tt[jj * 72 + c8] =
        *(const bf16x8*)&src[(size_t)(j0 + jj) * dil * 64 + c8];
  }
  __syncthreads();
  const int d = tid >> 2, pg = (tid & 3) * 16;
  union { bf16x8 v2[2]; unsigned short u[16]; } ob;
#pragma unroll
  for (int t = 0; t < 16; ++t) {
    const int pos = pg + t;
    const int w = pos & 31;
    const int jj = (pos & 32) | (((w >> 2) & 1) * 16 + (w >> 3) * 4 + (w & 3));
    ob.u[t] = Tt[jj * 72 + d];
  }
  *(bf16x8*)&dst[(size_t)d * Nk + j0 + pg] = ob.v2[0];
  *(bf16x8*)&dst[(size_t)d * Nk + j0 + pg + 8] = ob.v2[1];
}

// --------------------------- flash attention, all segments -----------------
// 2048 blocks of 64 q-rows. bx: x=bx&7 (XCD slice), r2=bx>>3: h=(r2&1)*8+x,
// unit=r2>>1: unit<64 seg2 (first => long blocks dispatch early), <96 seg1,
// else seg3. Each wave owns keys [w*Nk/4,(w+1)*Nk/4) with PRIVATE 8KB LDS
// (K 32x64-swizzled, V^T 64x32-swizzled) -> NO barriers in K-loop. Partial
// (o,l) merged across waves via LDS f32 atomics; output fully normalized.
__global__ __launch_bounds__(256, 3) void flash_all(
    const unsigned short* __restrict__ qkvb,
    const unsigned short* __restrict__ vt1, float* __restrict__ o1,
    const unsigned short* __restrict__ vt2, float* __restrict__ o2,
    const unsigned short* __restrict__ vt3, float* __restrict__ o3) {
  __shared__ unsigned short Smem[4 * 4096];   // per-wave: K 2048 | V 2048 shorts

  const int bx = blockIdx.x;
  const int x = bx & 7, r2 = bx >> 3;
  const int h = (r2 & 1) * 8 + x;
  const int unit = r2 >> 1;
  int z, qt;
  const unsigned short* vt;
  float* o;
  if (unit < 64)      { z = 1; qt = unit;      vt = vt2; o = o2; }
  else if (unit < 96) { z = 0; qt = unit - 64; vt = vt1; o = o1; }
  else                { z = 2; qt = unit - 96; vt = vt3; o = o3; }
  const int Nk = (z == 1) ? 4096 : 2048;
  const int dil = 1 << z;

  const int tid = threadIdx.x;
  const int wave = tid >> 6, lane = tid & 63;
  const int quad = lane >> 4, lc = lane & 15;

  const unsigned short* qh = qkvb + (size_t)h * 8192 * 64;
  const unsigned short* kh = qkvb + (size_t)(16 + h) * 8192 * 64;
  const unsigned short* vh = vt + (size_t)h * 64 * Nk;

  unsigned short* Kt = Smem + wave * 4096;    // 32 rows x 64 shorts, swizzled
  unsigned short* Vt = Kt + 2048;             // 64 rows x 32 shorts, swizzled

  // Q B-frags: 4 m-blocks of 16 q (block = 64 q rows, same for all waves)
  bf16x8 qf[4][2];
#pragma unroll
  for (int mb = 0; mb < 4; ++mb) {
    const size_t qrow = (size_t)(qt * 64 + mb * 16 + lc) * dil;
    qf[mb][0] = *(const bf16x8*)&qh[qrow * 64 + quad * 8];
    qf[mb][1] = *(const bf16x8*)&qh[qrow * 64 + quad * 8 + 32];
  }

  // constant all-ones A fragment (bf16 1.0) for the row-sum (l) MFMA
  union { bf16x8 v; unsigned short u[8]; } one_u;
#pragma unroll
  for (int t = 0; t < 8; ++t) one_u.u[t] = 0x3F80;
  const bf16x8 vone = one_u.v;

  f32x4 oacc[4][4] = {};   // [mb(q)][nb(d)]  O^T tiles: row=d, col=q
  f32x4 lacc[4] = {};      // [mb]            l per q (all rows identical)

  const int c0 = wave * (Nk >> 2);            // this wave's key chunk
  const int cLen = Nk >> 2;

  // staging lane maps (per-wave, 16B chunks)
  const int krow = lane >> 3, kch = lane & 7;      // K: rows i*8+krow
  const int vdr = lane >> 2, vch = lane & 3;       // V: rows i*16+vdr
  const int kswz = (kch ^ (krow & 7)) * 8;
  const int vswz = (vch ^ (vdr & 3)) * 8;

  bf16x8 kg[4], vg[4];
  // preload + stage tile 0
#pragma unroll
  for (int i = 0; i < 4; ++i) {
    kg[i] = *(const bf16x8*)&kh[(size_t)((c0 + i * 8 + krow) * dil) * 64 + kch * 8];
    vg[i] = *(const bf16x8*)&vh[(size_t)(i * 16 + vdr) * Nk + c0 + vch * 8];
  }
#pragma unroll
  for (int i = 0; i < 4; ++i) {
    *(bf16x8*)&Kt[(i * 8 + krow) * 64 + kswz] = kg[i];
    *(bf16x8*)&Vt[(i * 16 + vdr) * 32 + vswz] = vg[i];
  }

  for (int kb = 0; kb < cLen; kb += 32) {
    const bool more = (kb + 32 < cLen);
    if (more) {   // prefetch next 32-key tile into registers
      const int nk = c0 + kb + 32;
#pragma unroll
      for (int i = 0; i < 4; ++i) {
        kg[i] = *(const bf16x8*)&kh[(size_t)((nk + i * 8 + krow) * dil) * 64 + kch * 8];
        vg[i] = *(const bf16x8*)&vh[(size_t)(i * 16 + vdr) * Nk + nk + vch * 8];
      }
    }

    // ---- S^T = K.Q^T over 32 keys (2 key-blocks of 16) ----
    f32x4 st[2][4];
#pragma unroll
    for (int t = 0; t < 2; ++t) {
      const int row = t * 16 + lc;
      const bf16x8 ka0 = *(const bf16x8*)&Kt[row * 64 + ((quad ^ (lc & 7)) * 8)];
      const bf16x8 ka1 = *(const bf16x8*)&Kt[row * 64 + (((4 + quad) ^ (lc & 7)) * 8)];
#pragma unroll
      for (int mb = 0; mb < 4; ++mb) {
        f32x4 zz = {};
        zz = MFMA(ka0, qf[mb][0], zz);
        st[t][mb] = MFMA(ka1, qf[mb][1], zz);
      }
    }

    // ---- p = exp2(s); truncation-pack -> P^T B-frags (order == vt perm) ----
    bf16x8 pb[4];
#pragma unroll
    for (int mb = 0; mb < 4; ++mb) {
      union { bf16x8 v; unsigned int u[4]; } pu;
#pragma unroll
      for (int t = 0; t < 2; ++t) {
        const unsigned int a0 = __float_as_uint(EXP2(st[t][mb][0]));
        const unsigned int a1 = __float_as_uint(EXP2(st[t][mb][1]));
        const unsigned int a2 = __float_as_uint(EXP2(st[t][mb][2]));
        const unsigned int a3 = __float_as_uint(EXP2(st[t][mb][3]));
        pu.u[t * 2 + 0] = __builtin_amdgcn_perm(a1, a0, 0x07060302u);
        pu.u[t * 2 + 1] = __builtin_amdgcn_perm(a3, a2, 0x07060302u);
      }
      pb[mb] = pu.v;
    }

    // ---- O^T += V^T.P^T ; l += 1.P^T ----
#pragma unroll
    for (int nb = 0; nb < 4; ++nb) {
      const bf16x8 va = *(const bf16x8*)&Vt[(nb * 16 + lc) * 32 + ((quad ^ (lc & 3)) * 8)];
#pragma unroll
      for (int mb = 0; mb < 4; ++mb)
        oacc[mb][nb] = MFMA(va, pb[mb], oacc[mb][nb]);
    }
#pragma unroll
    for (int mb = 0; mb < 4; ++mb) lacc[mb] = MFMA(vone, pb[mb], lacc[mb]);

    if (more) {
      __builtin_amdgcn_s_waitcnt(0xC07F);   // lgkmcnt(0): LDS reads retired (WAR)
#pragma unroll
      for (int i = 0; i < 4; ++i) {
        *(bf16x8*)&Kt[(i * 8 + krow) * 64 + kswz] = kg[i];
        *(bf16x8*)&Vt[(i * 16 + vdr) * 32 + vswz] = vg[i];
      }
    }
  }

  // ---- merge partial (o,l) across the 4 waves via LDS atomics ----
  __syncthreads();                            // all waves done with staging LDS
  float* Wm = (float*)Smem;                   // [64 d][64 q] f32 (16KB)
  float* Wl = (float*)Smem + 4096;            // [64 q] f32
  for (int t = tid; t < 4160; t += 256) ((float*)Smem)[t] = 0.0f;
  __syncthreads();
#pragma unroll
  for (int mb = 0; mb < 4; ++mb) {
#pragma unroll
    for (int nb = 0; nb < 4; ++nb)
#pragma unroll
      for (int r = 0; r < 4; ++r)
        atomicAdd(&Wm[(nb * 16 + quad * 4 + r) * 64 + mb * 16 + lc], oacc[mb][nb][r]);
    if (quad == 0) atomicAdd(&Wl[mb * 16 + lc], lacc[mb][0]);
  }
  __syncthreads();

  // ---- normalize + transposed coalesced store (fully normalized output) ----
  const int q = tid >> 2, dg = tid & 3;
  const float inv = 1.0f / (3.0f * Wl[q]);    // fold mean over 3 segments
  const size_t base = (size_t)(qt * 64 + q) * 1024 + (size_t)h * 64 + dg * 16;
#pragma unroll
  for (int c2 = 0; c2 < 4; ++c2) {
    float4 v;
    v.x = Wm[(dg * 16 + c2 * 4 + 0) * 64 + q] * inv;
    v.y = Wm[(dg * 16 + c2 * 4 + 1) * 64 + q] * inv;
    v.z = Wm[(dg * 16 + c2 * 4 + 2) * 64 + q] * inv;
    v.w = Wm[(dg * 16 + c2 * 4 + 3) * 64 + q] * inv;
    *(float4*)&o[base + c2 * 4] = v;
  }
}

// ------------------- combine per-seg outputs -> bf16 a3 --------------------
__global__ void combine(const float* __restrict__ o1, const float* __restrict__ o2,
                        const float* __restrict__ o3,
                        unsigned short* __restrict__ a3b) {
  const int idx = blockIdx.x * 256 + threadIdx.x;   // 8192*128
  const int s = idx >> 7, e = (idx & 127) * 8;
  float acc[8] = {};
  if (s < 2048) {
    const float* p = &o1[(size_t)s * 1024 + e];
#pragma unroll
    for (int t = 0; t < 8; ++t) acc[t] += p[t];
  }
  if (!(s & 1)) {
    const float* p = &o2[(size_t)(s >> 1) * 1024 + e];
#pragma unroll
    for (int t = 0; t < 8; ++t) acc[t] += p[t];
  }
  if (!(s & 3)) {
    const float* p = &o3[(size_t)(s >> 2) * 1024 + e];
#pragma unroll
    for (int t = 0; t < 8; ++t) acc[t] += p[t];
  }
  union { bf16x8 v; unsigned short u[8]; } ob;
#pragma unroll
  for (int t = 0; t < 8; ++t) ob.u[t] = f2bf(acc[t]);
  *(bf16x8*)&a3b[(size_t)s * 1024 + e] = ob.v;
}

// ---------------------------------------------------------------------------
extern "C" void kernel_launch(void* const* d_in, const int* in_sizes, int n_in,
                              void* d_out, int out_size, void* d_ws, size_t ws_size,
                              hipStream_t stream) {
  const float* x     = (const float*)d_in[0];  // [8192][1024]
  const float* w_qkv = (const float*)d_in[1];  // [3072][1024]
  const float* b_qkv = (const float*)d_in[2];  // [3072]
  const float* w_out = (const float*)d_in[3];  // [1024][1024]
  const float* b_out = (const float*)d_in[4];  // [1024]
  float* out = (float*)d_out;                  // [8192][1024] f32

  char* ws = (char*)d_ws;
  unsigned short* qkvb  = (unsigned short*)(ws);             // Q,K,V: 50,331,648 B
  // V third (33.5M..50.3M) dead after transpose_v -> o1/o3:
  float*          o1    = (float*)(ws + 33554432);           //  8,388,608 B
  float*          o3    = (float*)(ws + 41943040);           //  8,388,608 B
  unsigned short* vt1   = (unsigned short*)(ws + 50331648);  //  4,194,304 B
  unsigned short* vt2   = (unsigned short*)(ws + 54525952);  //  8,388,608 B
  unsigned short* vt3   = (unsigned short*)(ws + 62914560);  //  4,194,304 B
  float*          o2    = (float*)(ws + 67108864);           // 16,777,216 B
  unsigned short* wqkvb = (unsigned short*)(ws + 83886080);  //  6,291,456 B
  unsigned short* woutb = (unsigned short*)(ws + 90177536);  //  2,097,152 B
  unsigned short* xb    = (unsigned short*)(ws + 92274688);  // 16,777,216 B
  unsigned short* a3b   = (unsigned short*)(ws + 50331648);  // over vt* (dead after flash)

  // fused f32->bf16 conversions (x, w_qkv, w_out)
  cvt_all<<<dim3(6144), dim3(256), 0, stream>>>(x, w_qkv, w_out, xb, wqkvb, woutb);

  // QKV projection -> [3][16][8192][64] (Q pre-scaled by log2e/8)
  gemm_bt<0><<<dim3(64, 24), dim3(256), 0, stream>>>(xb, wqkvb, b_qkv, qkvb, 3072, 1024);

  // V -> key-permuted transposed dilation copies
  transpose_v<<<dim3(128, 16), dim3(256), 0, stream>>>(qkvb + (size_t)32 * 8192 * 64,
                                                       vt1, vt2, vt3);

  // all 3 attention segments: 2048 barrier-free blocks of 64 q-rows
  flash_all<<<dim3(2048), dim3(256), 0, stream>>>(qkvb, vt1, o1, vt2, o2, vt3, o3);

  // sum segment outputs (normalization folded in flash) -> bf16
  combine<<<dim3(4096), dim3(256), 0, stream>>>(o1, o2, o3, a3b);

  // output projection: out = a3 . woutb^T + b_out   (f32 out)
  gemm_bt<1><<<dim3(64, 8), dim3(256), 0, stream>>>(a3b, woutb, b_out, out, 1024, 1024);
}